// Round 3
// baseline (269.244 us; speedup 1.0000x reference)
//
#include <hip/hip_runtime.h>
#include <hip/hip_bf16.h>
#include <cstdint>

#define B_ 16
#define S_ 2048
#define H_ 1024
#define D_ 64
#define R_ 2048
#define M_ (B_*S_)   // 32768 rows
#define N_ 128       // 2*D

typedef short short8 __attribute__((ext_vector_type(8)));
typedef float f32x4  __attribute__((ext_vector_type(4)));

__device__ __forceinline__ unsigned short f2bf(float f) {
    unsigned u = __builtin_bit_cast(unsigned, f);
    u += 0x7FFFu + ((u >> 16) & 1u);     // RNE
    return (unsigned short)(u >> 16);
}
__device__ __forceinline__ unsigned pk2(float a, float b) {      // RNE pack
    return (unsigned)f2bf(a) | ((unsigned)f2bf(b) << 16);
}
__device__ __forceinline__ unsigned pkt(float a, float b) {      // trunc pack, 2 VALU
    return (__builtin_bit_cast(unsigned, a) >> 16) |
           (__builtin_bit_cast(unsigned, b) & 0xFFFF0000u);
}
__device__ __forceinline__ float bflo(unsigned u) {
    return __builtin_bit_cast(float, u << 16);
}
__device__ __forceinline__ float bfhi(unsigned u) {
    return __builtin_bit_cast(float, u & 0xFFFF0000u);
}

// ---------------------------------------------------------------------------
// Kernel 0: Wt[n][k] = bf16(W[k][n]);  [128][1024] ushort.
// ---------------------------------------------------------------------------
__global__ void build_wt(const float* __restrict__ W, unsigned short* __restrict__ Wt) {
    int o = blockIdx.x * 256 + threadIdx.x;      // 131072
    int n = o >> 10, k = o & 1023;
    Wt[o] = f2bf(W[k * N_ + n]);
}

// ---------------------------------------------------------------------------
// Kernel 1: streaming MFMA GEMM + RoPE. One wave per block; tile = 16 rows x
// 64 cols (one q/k half). No LDS, no barriers: A fp32 -> VGPR (trunc-pack to
// bf16), Wt bf16 from L2 direct. Fully unrolled K: all addresses are
// immediate offsets from per-lane bases; compiler pipelines via vmcnt slack,
// TLP = 16 single-wave blocks/CU hides the rest.
// Grid 4096 = 256 groups x (8 xcd-phases x 2 col-halves); the two col-halves
// of a row-block share an XCD phase (blockIdx%8) for L2 reuse of A.
// ---------------------------------------------------------------------------
__launch_bounds__(64, 4)
__global__ void gemm_rope(const float* __restrict__ A,            // [M][1024]
                          const unsigned short* __restrict__ Wt,  // [128][1024] bf16
                          const float* __restrict__ bias,         // [128]
                          const int* __restrict__ pos_ids,        // [M]
                          unsigned* __restrict__ qk)              // [M][64] bf16x2
{
    const int lane = threadIdx.x;
    const int ln15 = lane & 15, quad = lane >> 4;
    const int idx  = blockIdx.x;
    const int u    = idx & 15;
    const int rb   = (idx >> 4) * 8 + (u & 7);   // row-block 0..2047
    const int ch   = u >> 3;                     // col half 0/1
    const int m0   = rb * 16;
    const int nb   = ch * 64;

    // per-lane bases; everything else is an immediate offset
    const char* a_base = (const char*)(A + (size_t)(m0 + ln15) * H_) + quad * 32;
    const char* w_base[4];
    #pragma unroll
    for (int j = 0; j < 4; j++)
        w_base[j] = (const char*)(Wt + (size_t)(nb + j * 16 + ln15) * H_) + quad * 16;

    f32x4 acc[4];
    #pragma unroll
    for (int j = 0; j < 4; j++) acc[j] = (f32x4)0.f;

    #pragma unroll
    for (int kc = 0; kc < 16; kc++) {
        const int ao = kc * 256;     // bytes per chunk along an A row (64 f32)
        const int wo = kc * 128;     // bytes per chunk along a Wt row (64 bf16)
        #pragma unroll
        for (int ks = 0; ks < 2; ks++) {
            // A frag: row ln15, k = kc*64 + ks*32 + quad*8 + 0..7
            f32x4 a0 = *(const f32x4*)(a_base + ao + ks * 128);
            f32x4 a1 = *(const f32x4*)(a_base + ao + ks * 128 + 16);
            int4 ai;
            ai.x = (int)pkt(a0[0], a0[1]);
            ai.y = (int)pkt(a0[2], a0[3]);
            ai.z = (int)pkt(a1[0], a1[1]);
            ai.w = (int)pkt(a1[2], a1[3]);
            const short8 af = __builtin_bit_cast(short8, ai);
            #pragma unroll
            for (int j = 0; j < 4; j++) {
                const short8 bf = *(const short8*)(w_base[j] + wo + ks * 64);
                acc[j] = __builtin_amdgcn_mfma_f32_16x16x32_bf16(af, bf, acc[j], 0, 0, 0);
            }
        }
    }

    // ---- epilogue: bias + RoPE + packed bf16 store
    // C/D layout: col(within tile j) = ln15, row = quad*4 + reg
    const int rbase = m0 + quad * 4;
    float bv[4], invr[4];
    #pragma unroll
    for (int j = 0; j < 4; j++) bv[j] = bias[nb + j * 16 + ln15];
    #pragma unroll
    for (int j = 0; j < 4; j++) {
        const float fi = (float)((j * 16 + ln15) >> 1);          // freq idx in half
        invr[j] = exp2f(fi * -0.41524101186092029f) * 0.15915494309189535f;
    }
    const bool odd = (ln15 & 1);
    #pragma unroll
    for (int reg = 0; reg < 4; reg++) {
        const int r = rbase + reg;
        const float pos = (float)pos_ids[r];
        #pragma unroll
        for (int j = 0; j < 4; j++) {
            float v = acc[j][reg] + bv[j];
            float p = __shfl_xor(v, 1, 64);                      // partner col c^1
            float fr = __builtin_amdgcn_fractf(pos * invr[j]);
            float s  = __builtin_amdgcn_sinf(fr);
            float co = __builtin_amdgcn_cosf(fr);
            float outv = odd ? fmaf(v, co, p * s) : fmaf(v, co, -p * s);
            float po = __shfl_xor(outv, 1, 64);
            if (!odd)
                qk[(size_t)r * 64 + ch * 32 + j * 8 + (ln15 >> 1)] = pk2(outv, po);
        }
    }
}

// ---------------------------------------------------------------------------
// Kernel 2: one wave per relation; qk is packed bf16 pairs.
// lanes 0..31: qw[i0] . kw[i2];  lanes 32..63: qw[i1] . kw[i3]
// ---------------------------------------------------------------------------
__global__ void gather_dot(const unsigned* __restrict__ qk, const int* __restrict__ rel,
                           const float* __restrict__ mask, float* __restrict__ out)
{
    const int w    = (blockIdx.x * 256 + threadIdx.x) >> 6;   // 0..32767
    const int lane = threadIdx.x & 63;
    const int b    = w >> 11;
    const int4 id4 = ((const int4*)rel)[w];
    const unsigned* base = qk + (size_t)b * S_ * 64;
    const int rq  = (lane < 32) ? id4.x : id4.y;
    const int rk  = (lane < 32) ? id4.z : id4.w;
    const int col = lane & 31;
    const unsigned uq = base[(size_t)rq * 64 + col];
    const unsigned uk = base[(size_t)rk * 64 + 32 + col];
    float v = bflo(uq) * bflo(uk) + bfhi(uq) * bfhi(uk);
    #pragma unroll
    for (int off = 32; off; off >>= 1) v += __shfl_xor(v, off, 64);
    if (lane == 0)
        out[w] = (v + (1.0f - mask[w]) * -1e12f) * 0.125f;
}

// ---------------------------------------------------------------------------
extern "C" void kernel_launch(void* const* d_in, const int* in_sizes, int n_in,
                              void* d_out, int out_size, void* d_ws, size_t ws_size,
                              hipStream_t stream) {
    const float* lhs  = (const float*)d_in[0];   // (B,S,H) fp32
    const float* W    = (const float*)d_in[1];   // (H,128) fp32
    const float* bias = (const float*)d_in[2];   // (128,)  fp32
    const int*   pos  = (const int*)d_in[3];     // (B,S)   int32
    const int*   rel  = (const int*)d_in[4];     // (B,R,4) int32
    const float* mask = (const float*)d_in[5];   // (B,R)   fp32
    float* out = (float*)d_out;                  // (B,R)   fp32

    unsigned short* Wt = (unsigned short*)d_ws;                      // 256 KiB
    unsigned* qk = (unsigned*)((char*)d_ws + (size_t)N_ * H_ * 2);   // 8 MiB bf16 pairs

    build_wt<<<512, 256, 0, stream>>>(W, Wt);
    gemm_rope<<<4096, 64, 0, stream>>>(lhs, Wt, bias, pos, qk);
    gather_dot<<<8192, 256, 0, stream>>>(qk, rel, mask, out);
}

// Round 4
// 253.990 us; speedup vs baseline: 1.0601x; 1.0601x over previous
//
#include <hip/hip_runtime.h>
#include <hip/hip_bf16.h>
#include <cstdint>

#define B_ 16
#define S_ 2048
#define H_ 1024
#define D_ 64
#define R_ 2048
#define M_ (B_*S_)   // 32768 rows
#define N_ 128       // 2*D

typedef short short8 __attribute__((ext_vector_type(8)));
typedef float f32x4  __attribute__((ext_vector_type(4)));

__device__ __forceinline__ unsigned short f2bf(float f) {
    unsigned u = __builtin_bit_cast(unsigned, f);
    u += 0x7FFFu + ((u >> 16) & 1u);     // RNE
    return (unsigned short)(u >> 16);
}
__device__ __forceinline__ unsigned pk2(float a, float b) {      // RNE pack
    return (unsigned)f2bf(a) | ((unsigned)f2bf(b) << 16);
}
__device__ __forceinline__ unsigned pkt(float a, float b) {      // trunc pack, 2 VALU
    return (__builtin_bit_cast(unsigned, a) >> 16) |
           (__builtin_bit_cast(unsigned, b) & 0xFFFF0000u);
}
__device__ __forceinline__ float bflo(unsigned u) {
    return __builtin_bit_cast(float, u << 16);
}
__device__ __forceinline__ float bfhi(unsigned u) {
    return __builtin_bit_cast(float, u & 0xFFFF0000u);
}

// ---------------------------------------------------------------------------
// Kernel 0: Wt[n][k] = bf16(W[k][n]);  [128][1024] ushort.
// ---------------------------------------------------------------------------
__global__ void build_wt(const float* __restrict__ W, unsigned short* __restrict__ Wt) {
    int o = blockIdx.x * 256 + threadIdx.x;      // 131072
    int n = o >> 10, k = o & 1023;
    Wt[o] = f2bf(W[k * N_ + n]);
}

// ---------------------------------------------------------------------------
// Kernel 1: streaming MFMA GEMM + RoPE, register-double-buffered.
// Wave tile = 32 rows x 64 cols (2 row-tiles x 4 col-tiles, 8 acc frags).
// K-loop: 32 chunks of k=32; chunk k+1's 8 loads (4 A f32x4-pairs + 4 W
// short8) issue as one independent batch while chunk k's 8 MFMAs run ->
// ~8 KB in flight per wave at every wait. 512 blocks x 4 waves = exactly
// 2 blocks/CU; wave pairs share A rows (col-half 0/1) for L1 reuse.
// ---------------------------------------------------------------------------
__launch_bounds__(256, 2)
__global__ void gemm_rope(const float* __restrict__ A,            // [M][1024]
                          const unsigned short* __restrict__ Wt,  // [128][1024] bf16
                          const float* __restrict__ bias,         // [128]
                          const int* __restrict__ pos_ids,        // [M]
                          unsigned* __restrict__ qk)              // [M][64] bf16x2
{
    const int lane  = threadIdx.x & 63;
    const int wavei = threadIdx.x >> 6;
    const int ln15  = lane & 15, quad = lane >> 4;
    const int g     = blockIdx.x * 4 + wavei;
    const int rb    = g >> 1;                    // row-stripe of 32 rows
    const int ch    = g & 1;                     // col half (q / k)
    const int m0    = rb * 32;
    const int nb    = ch * 64;

    // per-lane base pointers; all K-loop addressing is immediate offsets
    const char* a_base[2];
    #pragma unroll
    for (int r = 0; r < 2; r++)
        a_base[r] = (const char*)(A + (size_t)(m0 + r * 16 + ln15) * H_) + quad * 32;
    const char* w_base[4];
    #pragma unroll
    for (int j = 0; j < 4; j++)
        w_base[j] = (const char*)(Wt + (size_t)(nb + j * 16 + ln15) * H_) + quad * 16;

    f32x4 acc[8];                                // [r*4+j]
    #pragma unroll
    for (int i = 0; i < 8; i++) acc[i] = (f32x4)0.f;

    f32x4  a_f[2][4];                            // dbuf: [buf][r*2 + half]
    short8 w_f[2][4];                            // dbuf: [buf][j]

    // ---- preload chunk 0 into buf 0
    #pragma unroll
    for (int r = 0; r < 2; r++) {
        a_f[0][r * 2 + 0] = *(const f32x4*)(a_base[r] + 0);
        a_f[0][r * 2 + 1] = *(const f32x4*)(a_base[r] + 16);
    }
    #pragma unroll
    for (int j = 0; j < 4; j++) w_f[0][j] = *(const short8*)(w_base[j] + 0);

    #pragma unroll
    for (int kc = 0; kc < 32; kc++) {
        const int cur = kc & 1, nxt = cur ^ 1;
        if (kc + 1 < 32) {                       // batch-issue next chunk's loads
            const int ao = (kc + 1) * 128;       // bytes per chunk along A row
            const int wo = (kc + 1) * 64;        // bytes per chunk along Wt row
            #pragma unroll
            for (int r = 0; r < 2; r++) {
                a_f[nxt][r * 2 + 0] = *(const f32x4*)(a_base[r] + ao);
                a_f[nxt][r * 2 + 1] = *(const f32x4*)(a_base[r] + ao + 16);
            }
            #pragma unroll
            for (int j = 0; j < 4; j++)
                w_f[nxt][j] = *(const short8*)(w_base[j] + wo);
        }
        short8 af[2];
        #pragma unroll
        for (int r = 0; r < 2; r++) {
            const f32x4 a0 = a_f[cur][r * 2 + 0];
            const f32x4 a1 = a_f[cur][r * 2 + 1];
            int4 ai;
            ai.x = (int)pkt(a0[0], a0[1]);
            ai.y = (int)pkt(a0[2], a0[3]);
            ai.z = (int)pkt(a1[0], a1[1]);
            ai.w = (int)pkt(a1[2], a1[3]);
            af[r] = __builtin_bit_cast(short8, ai);
        }
        #pragma unroll
        for (int r = 0; r < 2; r++)
            #pragma unroll
            for (int j = 0; j < 4; j++)
                acc[r * 4 + j] = __builtin_amdgcn_mfma_f32_16x16x32_bf16(
                                     af[r], w_f[cur][j], acc[r * 4 + j], 0, 0, 0);
    }

    // ---- epilogue: bias + RoPE + packed bf16 store
    // C/D layout: col(within tile j) = ln15, row = quad*4 + reg
    float bv[4], invr[4];
    #pragma unroll
    for (int j = 0; j < 4; j++) bv[j] = bias[nb + j * 16 + ln15];
    #pragma unroll
    for (int j = 0; j < 4; j++) {
        const float fi = (float)((j * 16 + ln15) >> 1);          // freq idx in half
        invr[j] = exp2f(fi * -0.41524101186092029f) * 0.15915494309189535f;
    }
    const bool odd = (ln15 & 1);
    #pragma unroll
    for (int r = 0; r < 2; r++) {
        const int rb4 = m0 + r * 16 + quad * 4;
        #pragma unroll
        for (int reg = 0; reg < 4; reg++) {
            const int row = rb4 + reg;
            const float pos = (float)pos_ids[row];
            #pragma unroll
            for (int j = 0; j < 4; j++) {
                float v = acc[r * 4 + j][reg] + bv[j];
                float p = __shfl_xor(v, 1, 64);                  // partner col c^1
                float fr = __builtin_amdgcn_fractf(pos * invr[j]);
                float s  = __builtin_amdgcn_sinf(fr);
                float co = __builtin_amdgcn_cosf(fr);
                float outv = odd ? fmaf(v, co, p * s) : fmaf(v, co, -p * s);
                float po = __shfl_xor(outv, 1, 64);
                if (!odd)
                    qk[(size_t)row * 64 + ch * 32 + j * 8 + (ln15 >> 1)] = pk2(outv, po);
            }
        }
    }
}

// ---------------------------------------------------------------------------
// Kernel 2: one wave per relation; qk is packed bf16 pairs.
// lanes 0..31: qw[i0] . kw[i2];  lanes 32..63: qw[i1] . kw[i3]
// ---------------------------------------------------------------------------
__global__ void gather_dot(const unsigned* __restrict__ qk, const int* __restrict__ rel,
                           const float* __restrict__ mask, float* __restrict__ out)
{
    const int w    = (blockIdx.x * 256 + threadIdx.x) >> 6;   // 0..32767
    const int lane = threadIdx.x & 63;
    const int b    = w >> 11;
    const int4 id4 = ((const int4*)rel)[w];
    const unsigned* base = qk + (size_t)b * S_ * 64;
    const int rq  = (lane < 32) ? id4.x : id4.y;
    const int rk  = (lane < 32) ? id4.z : id4.w;
    const int col = lane & 31;
    const unsigned uq = base[(size_t)rq * 64 + col];
    const unsigned uk = base[(size_t)rk * 64 + 32 + col];
    float v = bflo(uq) * bflo(uk) + bfhi(uq) * bfhi(uk);
    #pragma unroll
    for (int off = 32; off; off >>= 1) v += __shfl_xor(v, off, 64);
    if (lane == 0)
        out[w] = (v + (1.0f - mask[w]) * -1e12f) * 0.125f;
}

// ---------------------------------------------------------------------------
extern "C" void kernel_launch(void* const* d_in, const int* in_sizes, int n_in,
                              void* d_out, int out_size, void* d_ws, size_t ws_size,
                              hipStream_t stream) {
    const float* lhs  = (const float*)d_in[0];   // (B,S,H) fp32
    const float* W    = (const float*)d_in[1];   // (H,128) fp32
    const float* bias = (const float*)d_in[2];   // (128,)  fp32
    const int*   pos  = (const int*)d_in[3];     // (B,S)   int32
    const int*   rel  = (const int*)d_in[4];     // (B,R,4) int32
    const float* mask = (const float*)d_in[5];   // (B,R)   fp32
    float* out = (float*)d_out;                  // (B,R)   fp32

    unsigned short* Wt = (unsigned short*)d_ws;                      // 256 KiB
    unsigned* qk = (unsigned*)((char*)d_ws + (size_t)N_ * H_ * 2);   // 8 MiB bf16 pairs

    build_wt<<<512, 256, 0, stream>>>(W, Wt);
    gemm_rope<<<512, 256, 0, stream>>>(lhs, Wt, bias, pos, qk);
    gather_dot<<<8192, 256, 0, stream>>>(qk, rel, mask, out);
}

// Round 5
// 232.125 us; speedup vs baseline: 1.1599x; 1.0942x over previous
//
#include <hip/hip_runtime.h>
#include <hip/hip_bf16.h>
#include <cstdint>

#define B_ 16
#define S_ 2048
#define H_ 1024
#define D_ 64
#define R_ 2048
#define M_ (B_*S_)   // 32768 rows
#define N_ 128       // 2*D
#define NC_ 16       // K chunks of 64

typedef short short8 __attribute__((ext_vector_type(8)));
typedef float f32x4  __attribute__((ext_vector_type(4)));

__device__ __forceinline__ unsigned short f2bf(float f) {
    unsigned u = __builtin_bit_cast(unsigned, f);
    u += 0x7FFFu + ((u >> 16) & 1u);     // RNE
    return (unsigned short)(u >> 16);
}
__device__ __forceinline__ unsigned pk2(float a, float b) {      // RNE pack
    return (unsigned)f2bf(a) | ((unsigned)f2bf(b) << 16);
}
__device__ __forceinline__ unsigned pkt(float a, float b) {      // trunc pack
    return (__builtin_bit_cast(unsigned, a) >> 16) |
           (__builtin_bit_cast(unsigned, b) & 0xFFFF0000u);
}
__device__ __forceinline__ float bflo(unsigned u) {
    return __builtin_bit_cast(float, u << 16);
}
__device__ __forceinline__ float bfhi(unsigned u) {
    return __builtin_bit_cast(float, u & 0xFFFF0000u);
}

typedef const __attribute__((address_space(1))) void gvoid_t;
typedef __attribute__((address_space(3))) void lvoid_t;
__device__ __forceinline__ void gload16(const void* g, void* l) {
    __builtin_amdgcn_global_load_lds((gvoid_t*)g, (lvoid_t*)l, 16, 0, 0);
}

// ---------------------------------------------------------------------------
// Kernel 0: Wt[n][k] = bf16(W[k][n]) via coalesced LDS transpose.
// Grid 32; block bk owns k-range [bk*32, bk*32+32). All accesses coalesced.
// ---------------------------------------------------------------------------
__global__ void build_wt(const float* __restrict__ W, unsigned short* __restrict__ Wt) {
    __shared__ unsigned short lt[N_ * 34];       // [n][34] pad -> odd word stride
    const int t  = threadIdx.x;
    const int bk = blockIdx.x;
    const int kr = t >> 7, cn = t & 127;
    #pragma unroll
    for (int i = 0; i < 16; i++) {               // read W rows coalesced
        const int k = i * 2 + kr;                // 0..31
        lt[cn * 34 + k] = f2bf(W[(size_t)(bk * 32 + k) * N_ + cn]);
    }
    __syncthreads();
    const int kk = t & 31, nr = t >> 5;          // 8 n-rows per iter
    #pragma unroll
    for (int i = 0; i < 16; i++) {               // write Wt rows coalesced
        const int n = i * 8 + nr;                // 0..127
        Wt[(size_t)n * H_ + bk * 32 + kk] = lt[n * 34 + kk];
    }
}

// ---------------------------------------------------------------------------
// Kernel 1: GEMM + RoPE. Block = 256 thr = 4 waves = (2 row-groups x 2 col-
// halves); block tile = 32 rows x 128 cols. 1024 blocks; A read exactly once.
// A (fp32) + W (bf16) double-buffer staged via global_load_lds, XOR-swizzled
// on the global side (16B granules, key = row&7) so ds_read_b128 fragment
// reads are 2-way-conflict-free. LDS = 48 KB -> 3 blocks/CU = 12 waves/CU;
// cross-block overlap covers the per-chunk barrier drain.
// ---------------------------------------------------------------------------
__launch_bounds__(256, 3)
__global__ void gemm_rope(const float* __restrict__ A,            // [M][1024]
                          const unsigned short* __restrict__ Wt,  // [128][1024] bf16
                          const float* __restrict__ bias,         // [128]
                          const int* __restrict__ pos_ids,        // [M]
                          unsigned* __restrict__ qk)              // [M][64] bf16x2
{
    __shared__ __align__(16) float          abuf[2][32 * 64];     // 2 x 8 KiB
    __shared__ __align__(16) unsigned short wbuf[2][N_ * 64];     // 2 x 16 KiB

    const int tid   = threadIdx.x;
    const int wavei = tid >> 6, lane = tid & 63;
    const int ln15  = lane & 15, quad = lane >> 4;
    const int rg    = wavei >> 1, ch = wavei & 1;
    const int m0    = blockIdx.x * 32;

    // ---- A staging: 2 calls; call c stages unit u = c*256+tid (16B units)
    const float* a_src[2]; int a_dst[2];
    #pragma unroll
    for (int c = 0; c < 2; c++) {
        const int u = c * 256 + tid;
        const int row = u >> 4, i = u & 15;
        a_src[c] = A + (size_t)(m0 + row) * H_ + ((i ^ (row & 7)) << 2);
        a_dst[c] = u << 2;                       // float offset
    }
    // ---- W staging: 4 calls; call t stages unit u = t*256+tid (16B units)
    const unsigned short* w_src[4]; int w_dst[4];
    #pragma unroll
    for (int t = 0; t < 4; t++) {
        const int u = t * 256 + tid;
        const int n = u >> 3, i = u & 7;
        w_src[t] = Wt + (size_t)n * H_ + ((i ^ (n & 7)) << 3);
        w_dst[t] = u << 3;                       // short offset
    }

    f32x4 acc[4];
    #pragma unroll
    for (int j = 0; j < 4; j++) acc[j] = (f32x4)0.f;

    // ---- prologue: stage chunk 0 into buf 0
    #pragma unroll
    for (int c = 0; c < 2; c++) gload16(a_src[c], &abuf[0][a_dst[c]]);
    #pragma unroll
    for (int t = 0; t < 4; t++) gload16(w_src[t], &wbuf[0][w_dst[t]]);

    const int arow = rg * 16 + ln15;             // block-row this lane's A-frag uses
    const int key  = ln15 & 7;

    for (int kc = 0; kc < NC_; kc++) {
        __syncthreads();                         // drains own DMA; swaps buffers
        if (kc + 1 < NC_) {
            const int nb = (kc + 1) & 1;
            #pragma unroll
            for (int c = 0; c < 2; c++)
                gload16(a_src[c] + (kc + 1) * 64, &abuf[nb][a_dst[c]]);
            #pragma unroll
            for (int t = 0; t < 4; t++)
                gload16(w_src[t] + (kc + 1) * 64, &wbuf[nb][w_dst[t]]);
        }
        const int cb = kc & 1;
        const float* ab = &abuf[cb][arow * 64];
        #pragma unroll
        for (int ks = 0; ks < 2; ks++) {
            const int g0 = ks * 8 + quad * 2;
            const f32x4 r0 = *(const f32x4*)(ab + ((g0 ^ key) << 2));
            const f32x4 r1 = *(const f32x4*)(ab + (((g0 + 1) ^ key) << 2));
            int4 ai;
            ai.x = (int)pkt(r0[0], r0[1]);
            ai.y = (int)pkt(r0[2], r0[3]);
            ai.z = (int)pkt(r1[0], r1[1]);
            ai.w = (int)pkt(r1[2], r1[3]);
            const short8 af = __builtin_bit_cast(short8, ai);
            const int p = (((ks * 4 + quad) ^ key) << 3);
            #pragma unroll
            for (int j = 0; j < 4; j++) {
                const int n = ch * 64 + j * 16 + ln15;
                const short8 bf = *(const short8*)(&wbuf[cb][n * 64 + p]);
                acc[j] = __builtin_amdgcn_mfma_f32_16x16x32_bf16(af, bf, acc[j], 0, 0, 0);
            }
        }
    }

    // ---- epilogue: bias + RoPE + packed bf16 store
    // C/D layout: col(within tile j) = ln15, row = quad*4 + reg
    const int nb = ch * 64;
    float bv[4], invr[4];
    #pragma unroll
    for (int j = 0; j < 4; j++) bv[j] = bias[nb + j * 16 + ln15];
    #pragma unroll
    for (int j = 0; j < 4; j++) {
        const float fi = (float)((j * 16 + ln15) >> 1);          // freq idx in half
        invr[j] = exp2f(fi * -0.41524101186092029f) * 0.15915494309189535f;
    }
    const bool odd = (ln15 & 1);
    const int rbase = m0 + rg * 16 + quad * 4;
    #pragma unroll
    for (int reg = 0; reg < 4; reg++) {
        const int row = rbase + reg;
        const float pos = (float)pos_ids[row];
        #pragma unroll
        for (int j = 0; j < 4; j++) {
            float v = acc[j][reg] + bv[j];
            float p = __shfl_xor(v, 1, 64);                      // partner col c^1
            float fr = __builtin_amdgcn_fractf(pos * invr[j]);
            float s  = __builtin_amdgcn_sinf(fr);
            float co = __builtin_amdgcn_cosf(fr);
            float outv = odd ? fmaf(v, co, p * s) : fmaf(v, co, -p * s);
            float po = __shfl_xor(outv, 1, 64);
            if (!odd)
                qk[(size_t)row * 64 + ch * 32 + j * 8 + (ln15 >> 1)] = pk2(outv, po);
        }
    }
}

// ---------------------------------------------------------------------------
// Kernel 2: one wave per relation; qk is packed bf16 pairs.
// lanes 0..31: qw[i0] . kw[i2];  lanes 32..63: qw[i1] . kw[i3]
// ---------------------------------------------------------------------------
__global__ void gather_dot(const unsigned* __restrict__ qk, const int* __restrict__ rel,
                           const float* __restrict__ mask, float* __restrict__ out)
{
    const int w    = (blockIdx.x * 256 + threadIdx.x) >> 6;   // 0..32767
    const int lane = threadIdx.x & 63;
    const int b    = w >> 11;
    const int4 id4 = ((const int4*)rel)[w];
    const unsigned* base = qk + (size_t)b * S_ * 64;
    const int rq  = (lane < 32) ? id4.x : id4.y;
    const int rk  = (lane < 32) ? id4.z : id4.w;
    const int col = lane & 31;
    const unsigned uq = base[(size_t)rq * 64 + col];
    const unsigned uk = base[(size_t)rk * 64 + 32 + col];
    float v = bflo(uq) * bflo(uk) + bfhi(uq) * bfhi(uk);
    #pragma unroll
    for (int off = 32; off; off >>= 1) v += __shfl_xor(v, off, 64);
    if (lane == 0)
        out[w] = (v + (1.0f - mask[w]) * -1e12f) * 0.125f;
}

// ---------------------------------------------------------------------------
extern "C" void kernel_launch(void* const* d_in, const int* in_sizes, int n_in,
                              void* d_out, int out_size, void* d_ws, size_t ws_size,
                              hipStream_t stream) {
    const float* lhs  = (const float*)d_in[0];   // (B,S,H) fp32
    const float* W    = (const float*)d_in[1];   // (H,128) fp32
    const float* bias = (const float*)d_in[2];   // (128,)  fp32
    const int*   pos  = (const int*)d_in[3];     // (B,S)   int32
    const int*   rel  = (const int*)d_in[4];     // (B,R,4) int32
    const float* mask = (const float*)d_in[5];   // (B,R)   fp32
    float* out = (float*)d_out;                  // (B,R)   fp32

    unsigned short* Wt = (unsigned short*)d_ws;                      // 256 KiB
    unsigned* qk = (unsigned*)((char*)d_ws + (size_t)N_ * H_ * 2);   // 8 MiB bf16 pairs

    build_wt<<<32, 256, 0, stream>>>(W, Wt);
    gemm_rope<<<1024, 256, 0, stream>>>(lhs, Wt, bias, pos, qk);
    gather_dot<<<8192, 256, 0, stream>>>(qk, rel, mask, out);
}

// Round 6
// 224.068 us; speedup vs baseline: 1.2016x; 1.0360x over previous
//
#include <hip/hip_runtime.h>
#include <hip/hip_bf16.h>
#include <cstdint>

#define B_ 16
#define S_ 2048
#define H_ 1024
#define D_ 64
#define R_ 2048
#define M_ (B_*S_)   // 32768 rows
#define N_ 128       // 2*D
#define NC_ 16       // K chunks of 64

typedef short short8 __attribute__((ext_vector_type(8)));
typedef float f32x4  __attribute__((ext_vector_type(4)));

__device__ __forceinline__ unsigned short f2bf(float f) {
    unsigned u = __builtin_bit_cast(unsigned, f);
    u += 0x7FFFu + ((u >> 16) & 1u);     // RNE
    return (unsigned short)(u >> 16);
}
__device__ __forceinline__ unsigned pk2(float a, float b) {      // RNE pack
    return (unsigned)f2bf(a) | ((unsigned)f2bf(b) << 16);
}
__device__ __forceinline__ unsigned pkt(float a, float b) {      // trunc pack
    return (__builtin_bit_cast(unsigned, a) >> 16) |
           (__builtin_bit_cast(unsigned, b) & 0xFFFF0000u);
}
__device__ __forceinline__ float bflo(unsigned u) {
    return __builtin_bit_cast(float, u << 16);
}
__device__ __forceinline__ float bfhi(unsigned u) {
    return __builtin_bit_cast(float, u & 0xFFFF0000u);
}

// ---------------------------------------------------------------------------
// Kernel 0: Wt[n][k] = bf16(W[k][n]) via coalesced LDS transpose.
// ---------------------------------------------------------------------------
__global__ void build_wt(const float* __restrict__ W, unsigned short* __restrict__ Wt) {
    __shared__ unsigned short lt[N_ * 34];
    const int t  = threadIdx.x;
    const int bk = blockIdx.x;
    const int kr = t >> 7, cn = t & 127;
    #pragma unroll
    for (int i = 0; i < 16; i++) {
        const int k = i * 2 + kr;
        lt[cn * 34 + k] = f2bf(W[(size_t)(bk * 32 + k) * N_ + cn]);
    }
    __syncthreads();
    const int kk = t & 31, nr = t >> 5;
    #pragma unroll
    for (int i = 0; i < 16; i++) {
        const int n = i * 8 + nr;
        Wt[(size_t)n * H_ + bk * 32 + kk] = lt[n * 34 + kk];
    }
}

// ---------------------------------------------------------------------------
// Kernel 1: GEMM + RoPE. Block = 256 thr = 4 waves (2 row-groups x 2 col-
// halves); tile = 64 rows x 128 cols; BK=64, 16 chunks, double-buffered.
// Staging path: buffer_load -> VGPR -> (A: pack fp32->bf16) -> ds_write_b128,
// XOR-swizzled 16B octets (octet o of row r at o^(r&7)) so every MFMA frag
// is one conflict-free ds_read_b128. One barrier per chunk; loads for chunk
// k+2 issue while writing k+1 and computing k. LDS 48 KB -> 3 blocks/CU;
// 512 blocks = single residency round (no tail).
// ---------------------------------------------------------------------------
__launch_bounds__(256, 3)
__global__ void gemm_rope(const float* __restrict__ A,            // [M][1024]
                          const unsigned short* __restrict__ Wt,  // [128][1024] bf16
                          const float* __restrict__ bias,         // [128]
                          const int* __restrict__ pos_ids,        // [M]
                          unsigned* __restrict__ qk)              // [M][64] bf16x2
{
    __shared__ __align__(16) unsigned short abuf[2][64 * 64];     // 2 x 8 KiB
    __shared__ __align__(16) unsigned short wbuf[2][N_ * 64];     // 2 x 16 KiB

    const int tid   = threadIdx.x;
    const int wavei = tid >> 6, lane = tid & 63;
    const int ln15  = lane & 15, quad = lane >> 4;
    const int rw    = wavei >> 1, cw = wavei & 1;
    const int m0    = blockIdx.x * 64;

    // ---- staging maps: unit u = octet (16B of bf16 / 32B of fp32)
    const float* a_src[2]; int a_dst[2];
    #pragma unroll
    for (int t = 0; t < 2; t++) {
        const int u = t * 256 + tid;
        const int r = u >> 3, oc = u & 7;
        a_src[t] = A + (size_t)(m0 + r) * H_ + oc * 8;            // 8 consecutive floats
        a_dst[t] = r * 64 + ((oc ^ (r & 7)) * 8);                 // ushort offset
    }
    const unsigned short* w_src[4]; int w_dst[4];
    #pragma unroll
    for (int t = 0; t < 4; t++) {
        const int u = t * 256 + tid;
        const int n = u >> 3, oc = u & 7;
        w_src[t] = Wt + (size_t)n * H_ + oc * 8;                  // 8 consecutive bf16
        w_dst[t] = n * 64 + ((oc ^ (n & 7)) * 8);
    }

    f32x4  ra[2][2];      // A staging regs: [iter][lo/hi f32x4]
    short8 rwv[4];        // W staging regs

    f32x4 acc[8];         // [rt*4 + j]
    #pragma unroll
    for (int i = 0; i < 8; i++) acc[i] = (f32x4)0.f;

    // ---- prologue: chunk0 -> buf0; then load chunk1 into regs
    #pragma unroll
    for (int t = 0; t < 2; t++) {
        ra[t][0] = *(const f32x4*)(a_src[t]);
        ra[t][1] = *(const f32x4*)(a_src[t] + 4);
    }
    #pragma unroll
    for (int t = 0; t < 4; t++) rwv[t] = *(const short8*)(w_src[t]);
    #pragma unroll
    for (int t = 0; t < 2; t++) {
        int4 p;
        p.x = (int)pkt(ra[t][0][0], ra[t][0][1]);
        p.y = (int)pkt(ra[t][0][2], ra[t][0][3]);
        p.z = (int)pkt(ra[t][1][0], ra[t][1][1]);
        p.w = (int)pkt(ra[t][1][2], ra[t][1][3]);
        *(short8*)(&abuf[0][a_dst[t]]) = __builtin_bit_cast(short8, p);
    }
    #pragma unroll
    for (int t = 0; t < 4; t++) *(short8*)(&wbuf[0][w_dst[t]]) = rwv[t];
    #pragma unroll
    for (int t = 0; t < 2; t++) {
        ra[t][0] = *(const f32x4*)(a_src[t] + 64);
        ra[t][1] = *(const f32x4*)(a_src[t] + 68);
    }
    #pragma unroll
    for (int t = 0; t < 4; t++) rwv[t] = *(const short8*)(w_src[t] + 64);

    const int key = ln15 & 7;

    for (int kc = 0; kc < NC_; kc++) {
        __syncthreads();                       // buf[kc&1] visible; buf[nxt] free
        if (kc + 1 < NC_) {                    // write chunk kc+1 (regs) -> buf[nxt]
            const int nb = (kc + 1) & 1;
            #pragma unroll
            for (int t = 0; t < 2; t++) {
                int4 p;
                p.x = (int)pkt(ra[t][0][0], ra[t][0][1]);
                p.y = (int)pkt(ra[t][0][2], ra[t][0][3]);
                p.z = (int)pkt(ra[t][1][0], ra[t][1][1]);
                p.w = (int)pkt(ra[t][1][2], ra[t][1][3]);
                *(short8*)(&abuf[nb][a_dst[t]]) = __builtin_bit_cast(short8, p);
            }
            #pragma unroll
            for (int t = 0; t < 4; t++) *(short8*)(&wbuf[nb][w_dst[t]]) = rwv[t];
        }
        if (kc + 2 < NC_) {                    // load chunk kc+2 -> regs (async)
            const int o = (kc + 2) * 64;
            #pragma unroll
            for (int t = 0; t < 2; t++) {
                ra[t][0] = *(const f32x4*)(a_src[t] + o);
                ra[t][1] = *(const f32x4*)(a_src[t] + o + 4);
            }
            #pragma unroll
            for (int t = 0; t < 4; t++) rwv[t] = *(const short8*)(w_src[t] + o);
        }
        // ---- compute chunk kc from buf[kc&1]
        const int cb = kc & 1;
        #pragma unroll
        for (int ks = 0; ks < 2; ks++) {
            const int oc = ((ks * 4 + quad) ^ key) * 8;
            short8 af[2];
            #pragma unroll
            for (int rt = 0; rt < 2; rt++)
                af[rt] = *(const short8*)(&abuf[cb][(rw * 32 + rt * 16 + ln15) * 64 + oc]);
            #pragma unroll
            for (int j = 0; j < 4; j++) {
                const short8 bf = *(const short8*)(&wbuf[cb][(cw * 64 + j * 16 + ln15) * 64 + oc]);
                #pragma unroll
                for (int rt = 0; rt < 2; rt++)
                    acc[rt * 4 + j] = __builtin_amdgcn_mfma_f32_16x16x32_bf16(
                                          af[rt], bf, acc[rt * 4 + j], 0, 0, 0);
            }
        }
    }

    // ---- epilogue: bias + RoPE + packed bf16 store
    // C/D layout: col(within tile j) = ln15, row = quad*4 + reg
    const int nb = cw * 64;
    float bv[4], invr[4];
    #pragma unroll
    for (int j = 0; j < 4; j++) bv[j] = bias[nb + j * 16 + ln15];
    #pragma unroll
    for (int j = 0; j < 4; j++) {
        const float fi = (float)((j * 16 + ln15) >> 1);          // freq idx in half
        invr[j] = exp2f(fi * -0.41524101186092029f) * 0.15915494309189535f;
    }
    const bool odd = (ln15 & 1);
    #pragma unroll
    for (int rt = 0; rt < 2; rt++) {
        const int rbase = m0 + rw * 32 + rt * 16 + quad * 4;
        #pragma unroll
        for (int reg = 0; reg < 4; reg++) {
            const int row = rbase + reg;
            const float pos = (float)pos_ids[row];
            #pragma unroll
            for (int j = 0; j < 4; j++) {
                float v = acc[rt * 4 + j][reg] + bv[j];
                float p = __shfl_xor(v, 1, 64);                  // partner col c^1
                float fr = __builtin_amdgcn_fractf(pos * invr[j]);
                float s  = __builtin_amdgcn_sinf(fr);
                float co = __builtin_amdgcn_cosf(fr);
                float outv = odd ? fmaf(v, co, p * s) : fmaf(v, co, -p * s);
                float po = __shfl_xor(outv, 1, 64);
                if (!odd)
                    qk[(size_t)row * 64 + cw * 32 + j * 8 + (ln15 >> 1)] = pk2(outv, po);
            }
        }
    }
}

// ---------------------------------------------------------------------------
// Kernel 2: one wave per relation; qk is packed bf16 pairs.
// lanes 0..31: qw[i0] . kw[i2];  lanes 32..63: qw[i1] . kw[i3]
// ---------------------------------------------------------------------------
__global__ void gather_dot(const unsigned* __restrict__ qk, const int* __restrict__ rel,
                           const float* __restrict__ mask, float* __restrict__ out)
{
    const int w    = (blockIdx.x * 256 + threadIdx.x) >> 6;   // 0..32767
    const int lane = threadIdx.x & 63;
    const int b    = w >> 11;
    const int4 id4 = ((const int4*)rel)[w];
    const unsigned* base = qk + (size_t)b * S_ * 64;
    const int rq  = (lane < 32) ? id4.x : id4.y;
    const int rk  = (lane < 32) ? id4.z : id4.w;
    const int col = lane & 31;
    const unsigned uq = base[(size_t)rq * 64 + col];
    const unsigned uk = base[(size_t)rk * 64 + 32 + col];
    float v = bflo(uq) * bflo(uk) + bfhi(uq) * bfhi(uk);
    #pragma unroll
    for (int off = 32; off; off >>= 1) v += __shfl_xor(v, off, 64);
    if (lane == 0)
        out[w] = (v + (1.0f - mask[w]) * -1e12f) * 0.125f;
}

// ---------------------------------------------------------------------------
extern "C" void kernel_launch(void* const* d_in, const int* in_sizes, int n_in,
                              void* d_out, int out_size, void* d_ws, size_t ws_size,
                              hipStream_t stream) {
    const float* lhs  = (const float*)d_in[0];   // (B,S,H) fp32
    const float* W    = (const float*)d_in[1];   // (H,128) fp32
    const float* bias = (const float*)d_in[2];   // (128,)  fp32
    const int*   pos  = (const int*)d_in[3];     // (B,S)   int32
    const int*   rel  = (const int*)d_in[4];     // (B,R,4) int32
    const float* mask = (const float*)d_in[5];   // (B,R)   fp32
    float* out = (float*)d_out;                  // (B,R)   fp32

    unsigned short* Wt = (unsigned short*)d_ws;                      // 256 KiB
    unsigned* qk = (unsigned*)((char*)d_ws + (size_t)N_ * H_ * 2);   // 8 MiB bf16 pairs

    build_wt<<<32, 256, 0, stream>>>(W, Wt);
    gemm_rope<<<512, 256, 0, stream>>>(lhs, Wt, bias, pos, qk);
    gather_dot<<<8192, 256, 0, stream>>>(qk, rel, mask, out);
}